// Round 2
// baseline (622.111 us; speedup 1.0000x reference)
//
#include <hip/hip_runtime.h>
#include <math.h>

// Problem constants
#define B_   64
#define T_   256
#define W_   20
#define NP_  6
#define NT_  12
#define CC_  32      // CONV_CH
#define FD_  8       // FRAG_DIM
#define PR_  64      // PROJ

__device__ __forceinline__ float sigmoidf_(float x) {
    return 1.0f / (1.0f + __expf(-x));
}
__device__ __forceinline__ float tanhf_(float x) {
    x = fminf(fmaxf(x, -15.0f), 15.0f);   // clamp so __expf never returns inf/inf
    float e = __expf(2.0f * x);
    return (e - 1.0f) / (e + 1.0f);
}

// -------------------------------------------------------------------------
// Kernel 1: per-window encoders + fragility + projection + LSTM input gates.
// One wave (64 threads) per (b,t) window; 16384 blocks.  (unchanged)
// -------------------------------------------------------------------------
__global__ __launch_bounds__(64) void encoder_kernel(
    const float* __restrict__ pressure, const float* __restrict__ torque,
    const float* __restrict__ frag,
    const float* __restrict__ pw1, const float* __restrict__ pb1,
    const float* __restrict__ pw2, const float* __restrict__ pb2,
    const float* __restrict__ tw1, const float* __restrict__ tb1,
    const float* __restrict__ tw2, const float* __restrict__ tb2,
    const float* __restrict__ fw,  const float* __restrict__ fb,
    const float* __restrict__ prw, const float* __restrict__ prb,
    const float* __restrict__ Wih, const float* __restrict__ bih,
    const float* __restrict__ bhh,
    float* __restrict__ xg)             // (B,T,256) output
{
    const int bt  = blockIdx.x;         // 0..16383
    const int b   = bt >> 8;            // T_=256
    const int tid = threadIdx.x;        // 0..63

    __shared__ __align__(16) float xwin[360];    // [0..119]=pressure 6x20, [120..359]=torque 12x20
    __shared__ __align__(16) float h1[1280];     // [0..639]=h1p 32x20, [640..1279]=h1t 32x20
    __shared__ __align__(16) float catb[72];     // pf(32) | tf(32) | ff(8)
    __shared__ __align__(16) float featsh[64];

    // ---- stage window, transposing [w][i] -> [i][w] ----
    const float* pin = pressure + (size_t)bt * (W_ * NP_);
    for (int idx = tid; idx < W_ * NP_; idx += 64) {
        int w = idx / NP_, i = idx - w * NP_;
        xwin[i * 20 + w] = pin[idx];
    }
    const float* tin = torque + (size_t)bt * (W_ * NT_);
    for (int idx = tid; idx < W_ * NT_; idx += 64) {
        int w = idx / NT_, i = idx - w * NT_;
        xwin[120 + i * 20 + w] = tin[idx];
    }
    if (tid < FD_) catb[64 + tid] = fmaxf(frag[b] * fw[tid] + fb[tid], 0.0f);
    __syncthreads();

    // ---- conv1 (valid, K=3): in (nin,20) -> relu -> (32,18) ----
    {
        const int  o   = tid & 31;
        const bool isp = tid < 32;
        const float* xin = xwin + (isp ? 0 : 120);
        const float* w1  = isp ? (pw1 + o * (NP_ * 3)) : (tw1 + o * (NT_ * 3));
        const float  bz  = isp ? pb1[o] : tb1[o];
        const int    nin = isp ? NP_ : NT_;
        float acc[18];
        #pragma unroll
        for (int l = 0; l < 18; ++l) acc[l] = bz;
        for (int i = 0; i < nin; ++i) {
            float4 xr4[5];
            const float4* xrow = (const float4*)(xin + i * 20);
            #pragma unroll
            for (int q = 0; q < 5; ++q) xr4[q] = xrow[q];
            const float* xr = (const float*)xr4;
            const float wk0 = w1[i * 3 + 0], wk1 = w1[i * 3 + 1], wk2 = w1[i * 3 + 2];
            #pragma unroll
            for (int l = 0; l < 18; ++l)
                acc[l] += xr[l] * wk0 + xr[l + 1] * wk1 + xr[l + 2] * wk2;
        }
        float* h1o = h1 + (isp ? 0 : 640) + o * 20;
        #pragma unroll
        for (int l = 0; l < 18; ++l) h1o[l] = fmaxf(acc[l], 0.0f);
    }
    __syncthreads();

    // ---- conv2 (32->32, K=3) + relu + mean over 16 positions ----
    {
        const int  o   = tid & 31;
        const bool isp = tid < 32;
        const float* h1i = h1 + (isp ? 0 : 640);
        const float* w2  = isp ? (pw2 + o * 96) : (tw2 + o * 96);
        const float  bz  = isp ? pb2[o] : tb2[o];
        float s[16];
        #pragma unroll
        for (int l = 0; l < 16; ++l) s[l] = bz;
        for (int i = 0; i < 32; ++i) {
            float4 hr4[5];
            const float4* hrow = (const float4*)(h1i + i * 20);
            #pragma unroll
            for (int q = 0; q < 5; ++q) hr4[q] = hrow[q];
            const float* hr = (const float*)hr4;
            const float wk0 = w2[i * 3 + 0], wk1 = w2[i * 3 + 1], wk2 = w2[i * 3 + 2];
            #pragma unroll
            for (int l = 0; l < 16; ++l)
                s[l] += hr[l] * wk0 + hr[l + 1] * wk1 + hr[l + 2] * wk2;
        }
        float m = 0.0f;
        #pragma unroll
        for (int l = 0; l < 16; ++l) m += fmaxf(s[l], 0.0f);
        catb[tid] = m * 0.0625f;
    }
    __syncthreads();

    // ---- projection 72 -> 64, relu ----
    {
        float acc = prb[tid];
        const float4* w4 = (const float4*)(prw + tid * 72);
        const float4* c4 = (const float4*)catb;
        #pragma unroll
        for (int q = 0; q < 18; ++q) {
            float4 w = w4[q], cv = c4[q];
            acc += w.x * cv.x + w.y * cv.y + w.z * cv.z + w.w * cv.w;
        }
        featsh[tid] = fmaxf(acc, 0.0f);
    }
    __syncthreads();

    // ---- xg = feat @ Wih.T + bih + bhh ----
    {
        float4 fr[16];
        const float4* f4 = (const float4*)featsh;
        #pragma unroll
        for (int q = 0; q < 16; ++q) fr[q] = f4[q];
        float* xgrow = xg + (size_t)bt * 256;
        #pragma unroll
        for (int gi = 0; gi < 4; ++gi) {
            const int g = tid + 64 * gi;
            const float4* w4 = (const float4*)(Wih + (size_t)g * 64);
            float acc = bih[g] + bhh[g];
            #pragma unroll
            for (int q = 0; q < 16; ++q) {
                float4 w = w4[q];
                acc += w.x * fr[q].x + w.y * fr[q].y + w.z * fr[q].z + w.w * fr[q].w;
            }
            xgrow[g] = acc;
        }
    }
}

// -------------------------------------------------------------------------
// Kernel 2: LSTM recurrence — SINGLE WAVE per batch element.
// 64 blocks x 64 threads. Lane j owns hidden unit j and keeps all four of
// its Whh rows (i,f,g,o) in 256 VGPRs. No cross-wave traffic -> the two
// __syncthreads are single-wave (near-free); h round-trips through LDS
// wave-synchronously. xg is prefetched 2 steps deep to hide HBM latency.
// -------------------------------------------------------------------------
__global__ __launch_bounds__(64) void lstm_kernel(
    const float* __restrict__ xg,     // (B,T,256), bias already included
    const float* __restrict__ Whh,    // (256,64)
    float* __restrict__ hout,         // (B,T,64)
    float* __restrict__ dout)         // full output buffer
{
    const int b   = blockIdx.x;
    const int tid = threadIdx.x;      // 0..63, hidden unit index

    __shared__ __align__(16) float hs[64];

    // load the 4 Whh rows for this hidden unit: rows tid, 64+tid, 128+tid, 192+tid
    float4 wi[16], wf[16], wg[16], wo[16];
    {
        const float4* ri = (const float4*)(Whh + (size_t)(tid)       * 64);
        const float4* rf = (const float4*)(Whh + (size_t)(64  + tid) * 64);
        const float4* rg = (const float4*)(Whh + (size_t)(128 + tid) * 64);
        const float4* ro = (const float4*)(Whh + (size_t)(192 + tid) * 64);
        #pragma unroll
        for (int q = 0; q < 16; ++q) { wi[q] = ri[q]; wf[q] = rf[q]; wg[q] = rg[q]; wo[q] = ro[q]; }
    }

    const float* xgrow = xg + (size_t)b * T_ * 256;
    float* hrow = hout + (size_t)b * T_ * 64;

    float c = 0.0f;
    hs[tid] = 0.0f;
    __syncthreads();

    // 2-deep xg prefetch pipeline: xc = step t, xn = step t+1
    float xc0 = xgrow[tid], xc1 = xgrow[64 + tid], xc2 = xgrow[128 + tid], xc3 = xgrow[192 + tid];
    float xn0 = xgrow[256 + tid], xn1 = xgrow[320 + tid], xn2 = xgrow[384 + tid], xn3 = xgrow[448 + tid];

    for (int t = 0; t < T_; ++t) {
        // issue prefetch for t+2 (clamped) — lands while we compute
        const int tp = (t + 2 < T_) ? (t + 2) : (T_ - 1);
        const float* xpf = xgrow + tp * 256 + tid;
        float xf0 = xpf[0], xf1 = xpf[64], xf2 = xpf[128], xf3 = xpf[192];

        // 256x64 matvec slice: 4 gates for hidden unit tid, 4 interleaved chains
        float ai = xc0, af = xc1, ag = xc2, ao = xc3;
        const float4* h4 = (const float4*)hs;
        #pragma unroll
        for (int q = 0; q < 16; ++q) {
            float4 hv = h4[q];   // wave-uniform broadcast read, conflict-free
            ai += wi[q].x * hv.x + wi[q].y * hv.y + wi[q].z * hv.z + wi[q].w * hv.w;
            af += wf[q].x * hv.x + wf[q].y * hv.y + wf[q].z * hv.z + wf[q].w * hv.w;
            ag += wg[q].x * hv.x + wg[q].y * hv.y + wg[q].z * hv.z + wg[q].w * hv.w;
            ao += wo[q].x * hv.x + wo[q].y * hv.y + wo[q].z * hv.z + wo[q].w * hv.w;
        }

        const float I = sigmoidf_(ai);
        const float F = sigmoidf_(af);
        const float G = tanhf_(ag);
        const float O = sigmoidf_(ao);
        c = F * c + I * G;
        const float h = O * tanhf_(c);

        __syncthreads();              // single-wave: cheap; old hs reads all done
        hs[tid] = h;
        hrow[t * 64 + tid] = h;       // coalesced 256B store
        __syncthreads();              // new h visible (forces lgkmcnt drain)

        xc0 = xn0; xc1 = xn1; xc2 = xn2; xc3 = xn3;
        xn0 = xf0; xn1 = xf1; xn2 = xf2; xn3 = xf3;
    }

    dout[B_ * T_ * 4 + b * 64 + tid]           = hs[tid];  // hT
    dout[B_ * T_ * 4 + B_ * 64 + b * 64 + tid] = c;        // cT
}

// -------------------------------------------------------------------------
// Kernel 3: head. out[bt,m] = sigmoid(h[bt,:] . hw[m,:] + hb[m]).  (unchanged)
// -------------------------------------------------------------------------
__global__ __launch_bounds__(256) void head_kernel(
    const float* __restrict__ hout, const float* __restrict__ hw,
    const float* __restrict__ hb, float* __restrict__ out)
{
    const int blk = blockIdx.x;
    const int tid = threadIdx.x;

    __shared__ __align__(16) float hsh[64 * 68];
    __shared__ __align__(16) float wsh[256];
    __shared__ float bsh[4];

    const float4* s4 = (const float4*)(hout + (size_t)blk * 64 * 64);
    float4* d4 = (float4*)hsh;
    for (int q = tid; q < 1024; q += 256) {
        int row = q >> 4, col = q & 15;
        d4[row * 17 + col] = s4[q];
    }
    if (tid < 64) ((float4*)wsh)[tid] = ((const float4*)hw)[tid];
    if (tid < 4)  bsh[tid] = hb[tid];
    __syncthreads();

    const int r = tid >> 2, m = tid & 3;
    const float4* hv = (const float4*)(hsh + r * 68);
    const float4* wv = (const float4*)(wsh + m * 64);
    float acc = bsh[m];
    #pragma unroll
    for (int q = 0; q < 16; ++q) {
        float4 a = hv[q], w = wv[q];
        acc += a.x * w.x + a.y * w.y + a.z * w.z + a.w * w.w;
    }
    out[(size_t)blk * 256 + tid] = sigmoidf_(acc);
}

extern "C" void kernel_launch(void* const* d_in, const int* in_sizes, int n_in,
                              void* d_out, int out_size, void* d_ws, size_t ws_size,
                              hipStream_t stream) {
    const float* pressure = (const float*)d_in[0];
    const float* torque   = (const float*)d_in[1];
    const float* frag     = (const float*)d_in[2];
    const float* pw1 = (const float*)d_in[3];
    const float* pb1 = (const float*)d_in[4];
    const float* pw2 = (const float*)d_in[5];
    const float* pb2 = (const float*)d_in[6];
    const float* tw1 = (const float*)d_in[7];
    const float* tb1 = (const float*)d_in[8];
    const float* tw2 = (const float*)d_in[9];
    const float* tb2 = (const float*)d_in[10];
    const float* fw  = (const float*)d_in[11];
    const float* fb  = (const float*)d_in[12];
    const float* prw = (const float*)d_in[13];
    const float* prb = (const float*)d_in[14];
    const float* Wih = (const float*)d_in[15];
    const float* Whh = (const float*)d_in[16];
    const float* bih = (const float*)d_in[17];
    const float* bhh = (const float*)d_in[18];
    const float* hw  = (const float*)d_in[19];
    const float* hb  = (const float*)d_in[20];

    float* out = (float*)d_out;

    // workspace: xg (B*T*256 f32 = 16 MB) | hout (B*T*64 f32 = 4 MB)
    float* xg   = (float*)d_ws;
    float* hout = xg + (size_t)B_ * T_ * 256;

    encoder_kernel<<<B_ * T_, 64, 0, stream>>>(
        pressure, torque, frag,
        pw1, pb1, pw2, pb2, tw1, tb1, tw2, tb2,
        fw, fb, prw, prb, Wih, bih, bhh, xg);

    lstm_kernel<<<B_, 64, 0, stream>>>(xg, Whh, hout, out);

    head_kernel<<<B_ * T_ / 64, 256, 0, stream>>>(hout, hw, hb, out);
}

// Round 3
// 584.465 us; speedup vs baseline: 1.0644x; 1.0644x over previous
//
#include <hip/hip_runtime.h>
#include <math.h>

// Problem constants
#define B_   64
#define T_   256
#define W_   20
#define NP_  6
#define NT_  12
#define CC_  32      // CONV_CH
#define FD_  8       // FRAG_DIM
#define PR_  64      // PROJ

typedef float v2f __attribute__((ext_vector_type(2)));

__device__ __forceinline__ float sigmoidf_(float x) {
    return 1.0f / (1.0f + __expf(-x));
}
__device__ __forceinline__ float tanhf_(float x) {
    x = fminf(fmaxf(x, -15.0f), 15.0f);   // clamp so __expf never returns inf/inf
    float e = __expf(2.0f * x);
    return (e - 1.0f) / (e + 1.0f);
}

// -------------------------------------------------------------------------
// Kernel 1: per-window encoders + fragility + projection + LSTM input gates.
// One wave per (b,t) window; 16384 blocks. Conv weights are hoisted into
// registers BEFORE the position loops (i-loops fully unrolled, constant
// indexing) so the inner loops are pure LDS-broadcast reads + FMAs.
// -------------------------------------------------------------------------
__global__ __launch_bounds__(64) void encoder_kernel(
    const float* __restrict__ pressure, const float* __restrict__ torque,
    const float* __restrict__ frag,
    const float* __restrict__ pw1, const float* __restrict__ pb1,
    const float* __restrict__ pw2, const float* __restrict__ pb2,
    const float* __restrict__ tw1, const float* __restrict__ tb1,
    const float* __restrict__ tw2, const float* __restrict__ tb2,
    const float* __restrict__ fw,  const float* __restrict__ fb,
    const float* __restrict__ prw, const float* __restrict__ prb,
    const float* __restrict__ Wih, const float* __restrict__ bih,
    const float* __restrict__ bhh,
    float* __restrict__ xg)             // (B,T,256) output
{
    const int bt  = blockIdx.x;         // 0..16383
    const int b   = bt >> 8;            // T_=256
    const int tid = threadIdx.x;        // 0..63
    const int  o   = tid & 31;
    const bool isp = tid < 32;

    __shared__ __align__(16) float xwin[360];    // [0..119]=pressure 6x20, [120..359]=torque 12x20
    __shared__ __align__(16) float h1[1280];     // [0..639]=h1p 32x20, [640..1279]=h1t 32x20
    __shared__ __align__(16) float catb[72];     // pf(32) | tf(32) | ff(8)
    __shared__ __align__(16) float featsh[64];

    // ---- preload conv1 weights into registers, zero-padded to 12 input rows ----
    float w1r[36];
    {
        const float* w1 = isp ? (pw1 + o * (NP_ * 3)) : (tw1 + o * (NT_ * 3));
        const int n3 = (isp ? NP_ : NT_) * 3;
        #pragma unroll
        for (int k = 0; k < 36; ++k) w1r[k] = (k < n3) ? w1[k] : 0.0f;  // predicated load
    }
    const float bz1 = isp ? pb1[o] : tb1[o];

    // ---- stage window, transposing [w][i] -> [i][w] ----
    const float* pin = pressure + (size_t)bt * (W_ * NP_);
    for (int idx = tid; idx < W_ * NP_; idx += 64) {
        int w = idx / NP_, i = idx - w * NP_;
        xwin[i * 20 + w] = pin[idx];
    }
    const float* tin = torque + (size_t)bt * (W_ * NT_);
    for (int idx = tid; idx < W_ * NT_; idx += 64) {
        int w = idx / NT_, i = idx - w * NT_;
        xwin[120 + i * 20 + w] = tin[idx];
    }
    if (tid < FD_) catb[64 + tid] = fmaxf(frag[b] * fw[tid] + fb[tid], 0.0f);
    __syncthreads();

    // ---- conv1 (valid, K=3): uniform 12-row loop (zeros kill the pad rows) ----
    {
        const float* xin = xwin + (isp ? 0 : 120);
        float acc[18];
        #pragma unroll
        for (int l = 0; l < 18; ++l) acc[l] = bz1;
        #pragma unroll
        for (int i = 0; i < 12; ++i) {
            float4 xr4[5];
            const float4* xrow = (const float4*)(xin + i * 20);
            #pragma unroll
            for (int q = 0; q < 5; ++q) xr4[q] = xrow[q];     // broadcast b128
            const float* xr = (const float*)xr4;
            const float wk0 = w1r[i * 3 + 0], wk1 = w1r[i * 3 + 1], wk2 = w1r[i * 3 + 2];
            #pragma unroll
            for (int l = 0; l < 18; ++l)
                acc[l] += xr[l] * wk0 + xr[l + 1] * wk1 + xr[l + 2] * wk2;
        }
        float* h1o = h1 + (isp ? 0 : 640) + o * 20;
        #pragma unroll
        for (int l = 0; l < 18; ++l) h1o[l] = fmaxf(acc[l], 0.0f);
    }

    // ---- preload conv2 weights (96 floats = 24 float4) into registers ----
    float4 w2r[24];
    {
        const float4* w2p = (const float4*)(isp ? (pw2 + o * 96) : (tw2 + o * 96));
        #pragma unroll
        for (int q = 0; q < 24; ++q) w2r[q] = w2p[q];
    }
    const float bz2 = isp ? pb2[o] : tb2[o];
    __syncthreads();

    // ---- conv2 (32->32, K=3) + relu + mean; weights constant-indexed regs ----
    {
        const float* h1i = h1 + (isp ? 0 : 640);
        const float* w2s = (const float*)w2r;
        float s[16];
        #pragma unroll
        for (int l = 0; l < 16; ++l) s[l] = bz2;
        #pragma unroll
        for (int i = 0; i < 32; ++i) {
            float4 hr4[5];
            const float4* hrow = (const float4*)(h1i + i * 20);
            #pragma unroll
            for (int q = 0; q < 5; ++q) hr4[q] = hrow[q];
            const float* hr = (const float*)hr4;
            const float wk0 = w2s[i * 3 + 0], wk1 = w2s[i * 3 + 1], wk2 = w2s[i * 3 + 2];
            #pragma unroll
            for (int l = 0; l < 16; ++l)
                s[l] += hr[l] * wk0 + hr[l + 1] * wk1 + hr[l + 2] * wk2;
        }
        float m = 0.0f;
        #pragma unroll
        for (int l = 0; l < 16; ++l) m += fmaxf(s[l], 0.0f);
        catb[tid] = m * 0.0625f;
    }
    __syncthreads();

    // ---- projection 72 -> 64, relu ----
    {
        float acc = prb[tid];
        const float4* w4 = (const float4*)(prw + tid * 72);
        const float4* c4 = (const float4*)catb;
        #pragma unroll
        for (int q = 0; q < 18; ++q) {
            float4 w = w4[q], cv = c4[q];
            acc += w.x * cv.x + w.y * cv.y + w.z * cv.z + w.w * cv.w;
        }
        featsh[tid] = fmaxf(acc, 0.0f);
    }
    __syncthreads();

    // ---- xg = feat @ Wih.T + bih + bhh ----
    {
        float4 fr[16];
        const float4* f4 = (const float4*)featsh;
        #pragma unroll
        for (int q = 0; q < 16; ++q) fr[q] = f4[q];
        float* xgrow = xg + (size_t)bt * 256;
        #pragma unroll
        for (int gi = 0; gi < 4; ++gi) {
            const int g = tid + 64 * gi;
            const float4* w4 = (const float4*)(Wih + (size_t)g * 64);
            float acc = bih[g] + bhh[g];
            #pragma unroll
            for (int q = 0; q < 16; ++q) {
                float4 w = w4[q];
                acc += w.x * fr[q].x + w.y * fr[q].y + w.z * fr[q].z + w.w * fr[q].w;
            }
            xgrow[g] = acc;
        }
    }
}

// -------------------------------------------------------------------------
// Kernel 2: LSTM recurrence — single wave per batch element, 1 wave/SIMD
// (__launch_bounds__(64,1) -> 512-VGPR budget so all 256 weight floats stay
// register-resident). Accumulation packed as float2 for v_pk_fma_f32.
// -------------------------------------------------------------------------
__global__ __launch_bounds__(64, 1) void lstm_kernel(
    const float* __restrict__ xg,     // (B,T,256), bias already included
    const float* __restrict__ Whh,    // (256,64)
    float* __restrict__ hout,         // (B,T,64)
    float* __restrict__ dout)         // full output buffer
{
    const int b   = blockIdx.x;
    const int tid = threadIdx.x;      // hidden unit index

    __shared__ __align__(16) float hs[64];

    // 4 Whh rows for this unit (i,f,g,o), as 32 float2 each -> 256 VGPRs
    v2f wi[32], wf[32], wg[32], wo[32];
    {
        const v2f* ri = (const v2f*)(Whh + (size_t)(tid)       * 64);
        const v2f* rf = (const v2f*)(Whh + (size_t)(64  + tid) * 64);
        const v2f* rg = (const v2f*)(Whh + (size_t)(128 + tid) * 64);
        const v2f* ro = (const v2f*)(Whh + (size_t)(192 + tid) * 64);
        #pragma unroll
        for (int q = 0; q < 32; ++q) { wi[q] = ri[q]; wf[q] = rf[q]; wg[q] = rg[q]; wo[q] = ro[q]; }
    }

    const float* xgrow = xg + (size_t)b * T_ * 256;
    float* hrow = hout + (size_t)b * T_ * 64;

    float c = 0.0f;
    hs[tid] = 0.0f;
    __syncthreads();

    // 2-deep xg prefetch pipeline
    float xc0 = xgrow[tid], xc1 = xgrow[64 + tid], xc2 = xgrow[128 + tid], xc3 = xgrow[192 + tid];
    float xn0 = xgrow[256 + tid], xn1 = xgrow[320 + tid], xn2 = xgrow[384 + tid], xn3 = xgrow[448 + tid];

    for (int t = 0; t < T_; ++t) {
        const int tp = (t + 2 < T_) ? (t + 2) : (T_ - 1);
        const float* xpf = xgrow + tp * 256 + tid;
        float xf0 = xpf[0], xf1 = xpf[64], xf2 = xpf[128], xf3 = xpf[192];

        // 4-gate matvec slice, float2-packed (v_pk_fma_f32): 128 pk-FMAs
        v2f ai = {xc0, 0.0f}, af = {xc1, 0.0f}, ag = {xc2, 0.0f}, ao = {xc3, 0.0f};
        const v2f* h2 = (const v2f*)hs;
        #pragma unroll
        for (int q = 0; q < 32; ++q) {
            v2f hv = h2[q];                      // wave-uniform broadcast read
            ai += wi[q] * hv;
            af += wf[q] * hv;
            ag += wg[q] * hv;
            ao += wo[q] * hv;
        }

        const float I = sigmoidf_(ai.x + ai.y);
        const float F = sigmoidf_(af.x + af.y);
        const float G = tanhf_(ag.x + ag.y);
        const float O = sigmoidf_(ao.x + ao.y);
        c = F * c + I * G;
        const float h = O * tanhf_(c);

        __syncthreads();              // single-wave: waitcnt only, no s_barrier
        hs[tid] = h;
        hrow[t * 64 + tid] = h;       // coalesced 256B store
        __syncthreads();

        xc0 = xn0; xc1 = xn1; xc2 = xn2; xc3 = xn3;
        xn0 = xf0; xn1 = xf1; xn2 = xf2; xn3 = xf3;
    }

    dout[B_ * T_ * 4 + b * 64 + tid]           = hs[tid];  // hT
    dout[B_ * T_ * 4 + B_ * 64 + b * 64 + tid] = c;        // cT
}

// -------------------------------------------------------------------------
// Kernel 3: head. out[bt,m] = sigmoid(h[bt,:] . hw[m,:] + hb[m]).  (unchanged)
// -------------------------------------------------------------------------
__global__ __launch_bounds__(256) void head_kernel(
    const float* __restrict__ hout, const float* __restrict__ hw,
    const float* __restrict__ hb, float* __restrict__ out)
{
    const int blk = blockIdx.x;
    const int tid = threadIdx.x;

    __shared__ __align__(16) float hsh[64 * 68];
    __shared__ __align__(16) float wsh[256];
    __shared__ float bsh[4];

    const float4* s4 = (const float4*)(hout + (size_t)blk * 64 * 64);
    float4* d4 = (float4*)hsh;
    for (int q = tid; q < 1024; q += 256) {
        int row = q >> 4, col = q & 15;
        d4[row * 17 + col] = s4[q];
    }
    if (tid < 64) ((float4*)wsh)[tid] = ((const float4*)hw)[tid];
    if (tid < 4)  bsh[tid] = hb[tid];
    __syncthreads();

    const int r = tid >> 2, m = tid & 3;
    const float4* hv = (const float4*)(hsh + r * 68);
    const float4* wv = (const float4*)(wsh + m * 64);
    float acc = bsh[m];
    #pragma unroll
    for (int q = 0; q < 16; ++q) {
        float4 a = hv[q], w = wv[q];
        acc += a.x * w.x + a.y * w.y + a.z * w.z + a.w * w.w;
    }
    out[(size_t)blk * 256 + tid] = sigmoidf_(acc);
}

extern "C" void kernel_launch(void* const* d_in, const int* in_sizes, int n_in,
                              void* d_out, int out_size, void* d_ws, size_t ws_size,
                              hipStream_t stream) {
    const float* pressure = (const float*)d_in[0];
    const float* torque   = (const float*)d_in[1];
    const float* frag     = (const float*)d_in[2];
    const float* pw1 = (const float*)d_in[3];
    const float* pb1 = (const float*)d_in[4];
    const float* pw2 = (const float*)d_in[5];
    const float* pb2 = (const float*)d_in[6];
    const float* tw1 = (const float*)d_in[7];
    const float* tb1 = (const float*)d_in[8];
    const float* tw2 = (const float*)d_in[9];
    const float* tb2 = (const float*)d_in[10];
    const float* fw  = (const float*)d_in[11];
    const float* fb  = (const float*)d_in[12];
    const float* prw = (const float*)d_in[13];
    const float* prb = (const float*)d_in[14];
    const float* Wih = (const float*)d_in[15];
    const float* Whh = (const float*)d_in[16];
    const float* bih = (const float*)d_in[17];
    const float* bhh = (const float*)d_in[18];
    const float* hw  = (const float*)d_in[19];
    const float* hb  = (const float*)d_in[20];

    float* out = (float*)d_out;

    // workspace: xg (B*T*256 f32 = 16 MB) | hout (B*T*64 f32 = 4 MB)
    float* xg   = (float*)d_ws;
    float* hout = xg + (size_t)B_ * T_ * 256;

    encoder_kernel<<<B_ * T_, 64, 0, stream>>>(
        pressure, torque, frag,
        pw1, pb1, pw2, pb2, tw1, tb1, tw2, tb2,
        fw, fb, prw, prb, Wih, bih, bhh, xg);

    lstm_kernel<<<B_, 64, 0, stream>>>(xg, Whh, hout, out);

    head_kernel<<<B_ * T_ / 64, 256, 0, stream>>>(hout, hw, hb, out);
}